// Round 1
// baseline (103.653 us; speedup 1.0000x reference)
//
#include <hip/hip_runtime.h>

#define KS 7
#define NG 16
#define PAD 3
#define NB 4
#define NC 64
#define NH 128
#define NW 128
#define NR 16
#define CG 4          // NC/NG
#define TILE 8
#define HALO 14       // TILE + 2*PAD
#define NPIX 64       // TILE*TILE
#define NTHREADS 256
#define KK 49         // KS*KS

__global__ __launch_bounds__(NTHREADS, 2)
void invol_fused(const float* __restrict__ x,
                 const float* __restrict__ w_reduce,
                 const float* __restrict__ b_reduce,
                 const float* __restrict__ w_span,
                 const float* __restrict__ b_span,
                 float* __restrict__ out) {
    __shared__ float xs[NC][HALO][HALO];   // 50176 B
    __shared__ float red_s[NR][NPIX];      // 4096 B

    const int t  = threadIdx.x;
    const int w0 = blockIdx.x * TILE;
    const int h0 = blockIdx.y * TILE;
    const int b  = blockIdx.z;

    // ---- Phase 1: stage x halo tile (zero-padded) ----
    const int total = NC * HALO * HALO;    // 12544
    for (int idx = t; idx < total; idx += NTHREADS) {
        int ww   = idx % HALO;
        int rest = idx / HALO;
        int hh   = rest % HALO;
        int c    = rest / HALO;
        int gh = h0 + hh - PAD;
        int gw = w0 + ww - PAD;
        float v = 0.f;
        if ((unsigned)gh < NH && (unsigned)gw < NW)
            v = x[((b * NC + c) * NH + gh) * NW + gw];
        xs[c][hh][ww] = v;
    }
    __syncthreads();

    // ---- Phase 2: reduce 1x1 conv + ReLU -> red_s[r][pixel] ----
    {
        int pixel = t & 63;
        int ph = pixel >> 3, pw = pixel & 7;
        int r0 = __builtin_amdgcn_readfirstlane(t >> 6) * 4;   // wave-uniform
        float a0 = b_reduce[r0 + 0];
        float a1 = b_reduce[r0 + 1];
        float a2 = b_reduce[r0 + 2];
        float a3 = b_reduce[r0 + 3];
        #pragma unroll
        for (int c = 0; c < NC; ++c) {
            float xv = xs[c][ph + PAD][pw + PAD];
            a0 = fmaf(w_reduce[(r0 + 0) * NC + c], xv, a0);
            a1 = fmaf(w_reduce[(r0 + 1) * NC + c], xv, a1);
            a2 = fmaf(w_reduce[(r0 + 2) * NC + c], xv, a2);
            a3 = fmaf(w_reduce[(r0 + 3) * NC + c], xv, a3);
        }
        red_s[r0 + 0][pixel] = fmaxf(a0, 0.f);
        red_s[r0 + 1][pixel] = fmaxf(a1, 0.f);
        red_s[r0 + 2][pixel] = fmaxf(a2, 0.f);
        red_s[r0 + 3][pixel] = fmaxf(a3, 0.f);
    }
    __syncthreads();

    // ---- Phase 3: span conv -> softmax -> involution gather ----
    #pragma unroll 1
    for (int it = 0; it < 4; ++it) {
        int item  = t + NTHREADS * it;     // 0..1023
        int pixel = item & 63;
        int g     = item >> 6;             // wave-uniform by construction
        int gu    = __builtin_amdgcn_readfirstlane(g);
        int ph = pixel >> 3, pw = pixel & 7;

        float rv[NR];
        #pragma unroll
        for (int r = 0; r < NR; ++r) rv[r] = red_s[r][pixel];

        const float* wg = w_span + gu * (KK * NR);   // uniform -> scalar loads
        const float* bg = b_span + gu * KK;

        float s[KK];
        #pragma unroll
        for (int k = 0; k < KK; ++k) {
            float acc = bg[k];
            #pragma unroll
            for (int r = 0; r < NR; ++r)
                acc = fmaf(wg[k * NR + r], rv[r], acc);
            s[k] = acc;
        }

        // softmax over the 49 taps (max-subtracted)
        float m = s[0];
        #pragma unroll
        for (int k = 1; k < KK; ++k) m = fmaxf(m, s[k]);
        float sum = 0.f;
        #pragma unroll
        for (int k = 0; k < KK; ++k) {
            float e = __expf(s[k] - m);
            s[k] = e;
            sum += e;
        }
        float inv = 1.0f / sum;

        // involution gather over the 7x7 window, 4 channels of this group
        float acc[CG] = {0.f, 0.f, 0.f, 0.f};
        #pragma unroll
        for (int i = 0; i < KS; ++i) {
            #pragma unroll
            for (int j = 0; j < KS; ++j) {
                float wt = s[i * KS + j];
                #pragma unroll
                for (int cc = 0; cc < CG; ++cc)
                    acc[cc] = fmaf(wt, xs[gu * CG + cc][ph + i][pw + j], acc[cc]);
            }
        }

        int h = h0 + ph, w = w0 + pw;
        #pragma unroll
        for (int cc = 0; cc < CG; ++cc)
            out[((b * NC + gu * CG + cc) * NH + h) * NW + w] = acc[cc] * inv;
    }
}

extern "C" void kernel_launch(void* const* d_in, const int* in_sizes, int n_in,
                              void* d_out, int out_size, void* d_ws, size_t ws_size,
                              hipStream_t stream) {
    const float* x        = (const float*)d_in[0];
    const float* w_reduce = (const float*)d_in[1];
    const float* b_reduce = (const float*)d_in[2];
    const float* w_span   = (const float*)d_in[3];
    const float* b_span   = (const float*)d_in[4];
    float* out = (float*)d_out;

    dim3 grid(NW / TILE, NH / TILE, NB);   // 16 x 16 x 4 = 1024 blocks
    dim3 block(NTHREADS);
    invol_fused<<<grid, block, 0, stream>>>(x, w_reduce, b_reduce,
                                            w_span, b_span, out);
}

// Round 2
// 82.151 us; speedup vs baseline: 1.2617x; 1.2617x over previous
//
#include <hip/hip_runtime.h>

#define KS 7
#define NG 16
#define PAD 3
#define NB 4
#define NC 64
#define NH 128
#define NW 128
#define HW (NH*NW)
#define NR 16
#define CG 4            // NC/NG
#define TILE 8
#define HALO 14         // TILE + 2*PAD
#define KK 49           // KS*KS

// ---------------- Kernel A: red[b][pix][r] = relu(w_reduce @ x + b_reduce) ----
__global__ __launch_bounds__(256)
void red_kernel(const float* __restrict__ x,
                const float* __restrict__ w_reduce,
                const float* __restrict__ b_reduce,
                float* __restrict__ red) {
    __shared__ float wT[NC][NR];           // transposed: wT[c][r]
    const int t = threadIdx.x;
    #pragma unroll
    for (int e = 0; e < 4; ++e) {
        int i = t * 4 + e;                 // 0..1023, coalesced
        wT[i & 63][i >> 6] = w_reduce[i];  // w_reduce[r*64+c] -> wT[c][r]
    }
    __syncthreads();

    const int p   = blockIdx.x * 256 + t;  // 0..65535
    const int b   = p >> 14;               // /16384
    const int pix = p & 16383;

    float acc[NR];
    #pragma unroll
    for (int r = 0; r < NR; ++r) acc[r] = b_reduce[r];   // uniform -> s_load

    const float* xp = x + (size_t)b * (NC * HW) + pix;
    #pragma unroll 16
    for (int c = 0; c < NC; ++c) {
        float xv = xp[(size_t)c * HW];     // coalesced across lanes
        const float4* wv = (const float4*)&wT[c][0];     // broadcast reads
        float4 w0 = wv[0], w1 = wv[1], w2 = wv[2], w3 = wv[3];
        acc[0]  = fmaf(w0.x, xv, acc[0]);  acc[1]  = fmaf(w0.y, xv, acc[1]);
        acc[2]  = fmaf(w0.z, xv, acc[2]);  acc[3]  = fmaf(w0.w, xv, acc[3]);
        acc[4]  = fmaf(w1.x, xv, acc[4]);  acc[5]  = fmaf(w1.y, xv, acc[5]);
        acc[6]  = fmaf(w1.z, xv, acc[6]);  acc[7]  = fmaf(w1.w, xv, acc[7]);
        acc[8]  = fmaf(w2.x, xv, acc[8]);  acc[9]  = fmaf(w2.y, xv, acc[9]);
        acc[10] = fmaf(w2.z, xv, acc[10]); acc[11] = fmaf(w2.w, xv, acc[11]);
        acc[12] = fmaf(w3.x, xv, acc[12]); acc[13] = fmaf(w3.y, xv, acc[13]);
        acc[14] = fmaf(w3.z, xv, acc[14]); acc[15] = fmaf(w3.w, xv, acc[15]);
    }
    #pragma unroll
    for (int r = 0; r < NR; ++r) acc[r] = fmaxf(acc[r], 0.f);

    float4* rp = (float4*)(red + (size_t)p * NR);        // 64B/lane, coalesced
    rp[0] = make_float4(acc[0],  acc[1],  acc[2],  acc[3]);
    rp[1] = make_float4(acc[4],  acc[5],  acc[6],  acc[7]);
    rp[2] = make_float4(acc[8],  acc[9],  acc[10], acc[11]);
    rp[3] = make_float4(acc[12], acc[13], acc[14], acc[15]);
}

// ---------------- Kernel B: span conv -> softmax -> involution gather ---------
// One 64-thread block per (b, g, 8x8 tile). g uniform -> scalar w_span loads.
__global__ __launch_bounds__(64, 4)
void invol_kernel(const float* __restrict__ x,
                  const float* __restrict__ w_span,
                  const float* __restrict__ b_span,
                  const float* __restrict__ red,
                  float* __restrict__ out) {
    __shared__ float xs[CG * HALO * HALO];   // 784 floats = 3136 B

    const int t  = threadIdx.x;              // 0..63
    const int ph = t >> 3, pw = t & 7;
    const int tileIdx = blockIdx.x;          // 0..255
    const int h0 = (tileIdx >> 4) * TILE;
    const int w0 = (tileIdx & 15) * TILE;
    const int g  = blockIdx.y;               // uniform (SGPR)
    const int b  = blockIdx.z;

    // ---- stage 4-channel halo tile (zero-padded) ----
    const float* xb = x + ((size_t)(b * NC + g * CG)) * HW;
    for (int idx = t; idx < CG * HALO * HALO; idx += 64) {
        int c   = idx / (HALO * HALO);
        int rem = idx - c * (HALO * HALO);
        int hh  = rem / HALO;
        int ww  = rem - hh * HALO;
        int gh = h0 + hh - PAD;
        int gw = w0 + ww - PAD;
        float v = 0.f;
        if ((unsigned)gh < NH && (unsigned)gw < NW)
            v = xb[(size_t)c * HW + gh * NW + gw];
        xs[idx] = v;
    }
    __syncthreads();

    // ---- load reduced features: 16 contiguous floats per pixel ----
    const int pixel = (h0 + ph) * NW + (w0 + pw);
    const float4* rp = (const float4*)(red + ((size_t)b * HW + pixel) * NR);
    float4 r0 = rp[0], r1 = rp[1], r2 = rp[2], r3 = rp[3];
    float rv[NR] = {r0.x, r0.y, r0.z, r0.w, r1.x, r1.y, r1.z, r1.w,
                    r2.x, r2.y, r2.z, r2.w, r3.x, r3.y, r3.z, r3.w};

    // ---- span conv: 49 logits (w_span through scalar pipe) ----
    const float* wg = w_span + (size_t)g * (KK * NR);
    const float* bg = b_span + (size_t)g * KK;
    float s[KK];
    #pragma unroll
    for (int k = 0; k < KK; ++k) {
        float a = bg[k];
        #pragma unroll
        for (int r = 0; r < NR; ++r)
            a = fmaf(wg[k * NR + r], rv[r], a);
        s[k] = a;
    }

    // ---- softmax over 49 taps ----
    float m = s[0];
    #pragma unroll
    for (int k = 1; k < KK; ++k) m = fmaxf(m, s[k]);
    float sum = 0.f;
    #pragma unroll
    for (int k = 0; k < KK; ++k) {
        float e = __expf(s[k] - m);
        s[k] = e;
        sum += e;
    }
    float inv = 1.0f / sum;

    // ---- involution gather: 7x7 window, 4 channels ----
    float a0 = 0.f, a1 = 0.f, a2 = 0.f, a3 = 0.f;
    #pragma unroll
    for (int i = 0; i < KS; ++i) {
        #pragma unroll
        for (int j = 0; j < KS; ++j) {
            float wt = s[i * KS + j];
            int base = (ph + i) * HALO + (pw + j);
            a0 = fmaf(wt, xs[0 * HALO * HALO + base], a0);
            a1 = fmaf(wt, xs[1 * HALO * HALO + base], a1);
            a2 = fmaf(wt, xs[2 * HALO * HALO + base], a2);
            a3 = fmaf(wt, xs[3 * HALO * HALO + base], a3);
        }
    }

    const int h = h0 + ph, w = w0 + pw;
    size_t ob = ((size_t)(b * NC + g * CG) * NH + h) * NW + w;
    out[ob]          = a0 * inv;
    out[ob + HW]     = a1 * inv;
    out[ob + 2 * HW] = a2 * inv;
    out[ob + 3 * HW] = a3 * inv;
}

extern "C" void kernel_launch(void* const* d_in, const int* in_sizes, int n_in,
                              void* d_out, int out_size, void* d_ws, size_t ws_size,
                              hipStream_t stream) {
    const float* x        = (const float*)d_in[0];
    const float* w_reduce = (const float*)d_in[1];
    const float* b_reduce = (const float*)d_in[2];
    const float* w_span   = (const float*)d_in[3];
    const float* b_span   = (const float*)d_in[4];
    float* out = (float*)d_out;
    float* red = (float*)d_ws;               // needs 4 MB (B*H*W*16 fp32)

    red_kernel<<<dim3(NB * HW / 256), 256, 0, stream>>>(x, w_reduce, b_reduce, red);

    dim3 gridB(256, NG, NB);                 // (tiles, groups, batch) = 16384 blocks
    invol_kernel<<<gridB, 64, 0, stream>>>(x, w_span, b_span, red, out);
}